// Round 2
// baseline (655.752 us; speedup 1.0000x reference)
//
#include <hip/hip_runtime.h>

typedef unsigned short u16;
typedef short bf16x8 __attribute__((ext_vector_type(8)));
typedef float floatx4 __attribute__((ext_vector_type(4)));

// ---------- bf16 helpers (bit-level RNE) --------------------------------------
static __device__ __forceinline__ u16 f2bf(float f) {
  unsigned int u = __float_as_uint(f);
  unsigned int lsb = (u >> 16) & 1u;
  u += 0x7FFFu + lsb;                 // round-to-nearest-even
  return (u16)(u >> 16);
}
static __device__ __forceinline__ float bf2f(u16 u) {
  return __uint_as_float(((unsigned int)u) << 16);
}

// ---------- fp32 [R][C] -> transposed split-bf16 hi/lo [C][R] ------------------
template<int WANT_LO>
__global__ __launch_bounds__(256)
void split_transpose_f32(const float* __restrict__ in, u16* __restrict__ hi,
                         u16* __restrict__ lo, int R, int C) {
  __shared__ float t[32][33];
  const int r0 = blockIdx.y * 32, c0 = blockIdx.x * 32;
  const int tid = threadIdx.x;
  const int lr = tid >> 3;            // 0..31
  const int lc = (tid & 7) * 4;       // 0,4,..,28
  float4 v = *(const float4*)(in + (size_t)(r0 + lr) * C + c0 + lc);
  t[lr][lc + 0] = v.x; t[lr][lc + 1] = v.y; t[lr][lc + 2] = v.z; t[lr][lc + 3] = v.w;
  __syncthreads();
  u16 ph[4], pl[4];
#pragma unroll
  for (int j = 0; j < 4; j++) {
    float f = t[lc + j][lr];
    ph[j] = f2bf(f);
    if (WANT_LO) pl[j] = f2bf(f - bf2f(ph[j]));
  }
  const size_t o = (size_t)(c0 + lr) * R + r0 + lc;
  *(uint2*)(hi + o) = *(uint2*)ph;
  if (WANT_LO) *(uint2*)(lo + o) = *(uint2*)pl;
}

// ---------- fp32 [n] -> split-bf16 hi/lo (elementwise) -------------------------
__global__ __launch_bounds__(256)
void split_f32(const float* __restrict__ in, u16* __restrict__ hi,
               u16* __restrict__ lo) {
  const size_t i4 = ((size_t)blockIdx.x * 256 + threadIdx.x) * 4;
  float4 v = *(const float4*)(in + i4);
  float f[4] = {v.x, v.y, v.z, v.w};
  u16 ph[4], pl[4];
#pragma unroll
  for (int j = 0; j < 4; j++) {
    ph[j] = f2bf(f[j]);
    pl[j] = f2bf(f[j] - bf2f(ph[j]));
  }
  *(uint2*)(hi + i4) = *(uint2*)ph;
  *(uint2*)(lo + i4) = *(uint2*)pl;
}

// ---------- generic MFMA GEMM: C[M,N] = A[M,K] * B^T  (B stored [N][K]) --------
// A_SPLIT/B_SPLIT: hi/lo bf16 pair -> 3-term product (hh + hl + lh).
// OUT_MODE: 0 = bf16, 1 = split bf16 (hi->C0, lo->C1), 2 = fp32,
//           3 = bf16 transposed V-store: vT[b][n][t], b=m>>11, t=m&2047 (2048x1024 hard)
// Tile: 64x64 per 256-thread block (4 waves, 2x2 x mfma_f32_16x16x32_bf16), BK=32.
template<int A_SPLIT, int B_SPLIT, int OUT_MODE, int HAS_BIAS>
__global__ __launch_bounds__(256)
void gemm_mfma(const u16* __restrict__ Ahi, const u16* __restrict__ Alo,
               const u16* __restrict__ Bhi, const u16* __restrict__ Blo,
               const float* __restrict__ bias,
               void* __restrict__ C0, void* __restrict__ C1,
               int M, int N, int K,
               long long aB, long long bB, long long cB, float scale) {
  // LDS stride 40 (=32+8) keeps 16B alignment; 2-way bank aliasing is free.
  __shared__ __align__(16) u16 As[2][64 * 40];
  __shared__ __align__(16) u16 Bs[2][64 * 40];

  const int bz = blockIdx.z;
  const u16* A0 = Ahi + (size_t)bz * aB;
  const u16* A1 = A_SPLIT ? (Alo + (size_t)bz * aB) : (const u16*)nullptr;
  const u16* B0 = Bhi + (size_t)bz * bB;
  const u16* B1 = B_SPLIT ? (Blo + (size_t)bz * bB) : (const u16*)nullptr;

  const int m0 = blockIdx.y * 64;
  const int n0 = blockIdx.x * 64;
  const int tid = threadIdx.x;
  const int lr = tid >> 2;            // 0..63
  const int lc = (tid & 3) * 8;       // 0,8,16,24

  const int lane = tid & 63;
  const int w = tid >> 6;
  const int wm = (w >> 1) * 32, wn = (w & 1) * 32;
  const int r = lane & 15, quad = lane >> 4;

  floatx4 acc[2][2] = {};

  for (int k0 = 0; k0 < K; k0 += 32) {
    const size_t aoff = (size_t)(m0 + lr) * K + k0 + lc;
    const size_t boff = (size_t)(n0 + lr) * K + k0 + lc;
    uint4 av0 = *(const uint4*)(A0 + aoff);
    uint4 bv0 = *(const uint4*)(B0 + boff);
    uint4 av1, bv1;
    if (A_SPLIT) av1 = *(const uint4*)(A1 + aoff);
    if (B_SPLIT) bv1 = *(const uint4*)(B1 + boff);
    __syncthreads();                  // prior iter's LDS reads complete
    *(uint4*)&As[0][lr * 40 + lc] = av0;
    *(uint4*)&Bs[0][lr * 40 + lc] = bv0;
    if (A_SPLIT) *(uint4*)&As[1][lr * 40 + lc] = av1;
    if (B_SPLIT) *(uint4*)&Bs[1][lr * 40 + lc] = bv1;
    __syncthreads();
#pragma unroll
    for (int i = 0; i < 2; i++) {
      bf16x8 a0 = *(const bf16x8*)&As[0][(wm + i * 16 + r) * 40 + quad * 8];
      bf16x8 a1;
      if (A_SPLIT) a1 = *(const bf16x8*)&As[1][(wm + i * 16 + r) * 40 + quad * 8];
#pragma unroll
      for (int j = 0; j < 2; j++) {
        bf16x8 b0 = *(const bf16x8*)&Bs[0][(wn + j * 16 + r) * 40 + quad * 8];
        acc[i][j] = __builtin_amdgcn_mfma_f32_16x16x32_bf16(a0, b0, acc[i][j], 0, 0, 0);
        if (A_SPLIT && B_SPLIT) {
          bf16x8 b1 = *(const bf16x8*)&Bs[1][(wn + j * 16 + r) * 40 + quad * 8];
          acc[i][j] = __builtin_amdgcn_mfma_f32_16x16x32_bf16(a0, b1, acc[i][j], 0, 0, 0);
          acc[i][j] = __builtin_amdgcn_mfma_f32_16x16x32_bf16(a1, b0, acc[i][j], 0, 0, 0);
        }
      }
    }
  }

  // epilogue: D[m = quad*4+ii][n = r] per 16x16 fragment (m89-verified mapping)
#pragma unroll
  for (int i = 0; i < 2; i++) {
    const int mbase = m0 + wm + i * 16 + quad * 4;
#pragma unroll
    for (int j = 0; j < 2; j++) {
      const int col = n0 + wn + j * 16 + r;
      float bvs = 0.f;
      if (HAS_BIAS) bvs = bias[col];
      if (OUT_MODE == 3) {
        u16 pk[4];
#pragma unroll
        for (int ii = 0; ii < 4; ii++) pk[ii] = f2bf(acc[i][j][ii] * scale + bvs);
        const size_t idx = (size_t)(mbase >> 11) * (2048 * 1024) + (size_t)col * 2048 + (mbase & 2047);
        *(uint2*)((u16*)C0 + idx) = *(uint2*)pk;
      } else {
        u16* Cb = (u16*)C0 + (size_t)bz * cB;
        float* Cf = (float*)C0 + (size_t)bz * cB;
        u16* Cl = (OUT_MODE == 1) ? ((u16*)C1 + (size_t)bz * cB) : (u16*)nullptr;
#pragma unroll
        for (int ii = 0; ii < 4; ii++) {
          const float v = acc[i][j][ii] * scale + bvs;
          const size_t idx = (size_t)(mbase + ii) * N + col;
          if (OUT_MODE == 0) {
            Cb[idx] = f2bf(v);
          } else if (OUT_MODE == 1) {
            const u16 h = f2bf(v);
            Cb[idx] = h;
            Cl[idx] = f2bf(v - bf2f(h));
          } else if (OUT_MODE == 2) {
            Cf[idx] = v;
          }
        }
      }
    }
  }
}

// ---------- row softmax over 2048 fp32 scores, in place + bf16 copy ------------
__global__ __launch_bounds__(256)
void softmax_rows(float* __restrict__ S, u16* __restrict__ Pb) {
  const int row = blockIdx.x;
  float* s = S + (size_t)row * 2048;
  const int tid = threadIdx.x;
  const int w = tid >> 6;
  __shared__ float redm[4];
  __shared__ float reds[4];

  float v[8];
  float mx = -1e30f;
#pragma unroll
  for (int i = 0; i < 8; i++) {
    v[i] = s[tid + 256 * i];
    mx = fmaxf(mx, v[i]);
  }
#pragma unroll
  for (int o = 32; o > 0; o >>= 1) mx = fmaxf(mx, __shfl_xor(mx, o, 64));
  if ((tid & 63) == 0) redm[w] = mx;
  __syncthreads();
  mx = fmaxf(fmaxf(redm[0], redm[1]), fmaxf(redm[2], redm[3]));

  float sum = 0.f;
#pragma unroll
  for (int i = 0; i < 8; i++) {
    v[i] = __expf(v[i] - mx);
    sum += v[i];
  }
#pragma unroll
  for (int o = 32; o > 0; o >>= 1) sum += __shfl_xor(sum, o, 64);
  if ((tid & 63) == 0) reds[w] = sum;
  __syncthreads();
  sum = reds[0] + reds[1] + reds[2] + reds[3];
  const float rs = 1.0f / sum;
#pragma unroll
  for (int i = 0; i < 8; i++) {
    const float p = v[i] * rs;
    s[tid + 256 * i] = p;                              // fp32 p -> d_out (in place)
    Pb[(size_t)row * 2048 + tid + 256 * i] = f2bf(p);  // bf16 p for context GEMM
  }
}

// ---------- launch ------------------------------------------------------------
extern "C" void kernel_launch(void* const* d_in, const int* in_sizes, int n_in,
                              void* d_out, int out_size, void* d_ws, size_t ws_size,
                              hipStream_t stream) {
  const float* x  = (const float*)d_in[0];
  const float* wq = (const float*)d_in[1];
  const float* bq = (const float*)d_in[2];
  const float* wk = (const float*)d_in[3];
  const float* bk = (const float*)d_in[4];
  const float* wv = (const float*)d_in[5];
  const float* bv = (const float*)d_in[6];
  const float* wp = (const float*)d_in[7];
  const float* bp = (const float*)d_in[8];

  const size_t MB = 1024 * 1024;
  char* ws = (char*)d_ws;
  u16* wqThi = (u16*)(ws + 0 * MB);          // 2 MB each (1024x1024 bf16)
  u16* wqTlo = (u16*)(ws + 2 * MB);
  u16* wkThi = (u16*)(ws + 4 * MB);
  u16* wkTlo = (u16*)(ws + 6 * MB);
  u16* wvThi = (u16*)(ws + 8 * MB);
  u16* wpThi = (u16*)(ws + 10 * MB);
  u16* xhi   = (u16*)(ws + 12 * MB);         // 16 MB each (8192x1024 bf16)
  u16* xlo   = (u16*)(ws + 28 * MB);
  u16* qhi   = (u16*)(ws + 44 * MB);
  u16* qlo   = (u16*)(ws + 60 * MB);
  u16* khi   = (u16*)(ws + 76 * MB);
  u16* klo   = (u16*)(ws + 92 * MB);
  u16* vT    = (u16*)(ws + 108 * MB);        // [b][1024][2048] bf16, 16 MB
  u16* ctx   = qhi;                          // overlay: q dead after scores
  u16* pbf   = khi;                          // overlay: k dead after scores (32 MB)
  // total ws footprint: 124 MB

  float* outp = (float*)d_out;               // [4,2048,1024] fp32
  float* scf  = (float*)d_out + 8388608;     // scores -> softmax in place -> p fp32

  const dim3 blk(256);

  // weights: fp32 [K][N] -> split-bf16 transposed [N][K]
  split_transpose_f32<1><<<dim3(32, 32), blk, 0, stream>>>(wq, wqThi, wqTlo, 1024, 1024);
  split_transpose_f32<1><<<dim3(32, 32), blk, 0, stream>>>(wk, wkThi, wkTlo, 1024, 1024);
  split_transpose_f32<0><<<dim3(32, 32), blk, 0, stream>>>(wv, wvThi, nullptr, 1024, 1024);
  split_transpose_f32<0><<<dim3(32, 32), blk, 0, stream>>>(wp, wpThi, nullptr, 1024, 1024);
  // x: fp32 -> split-bf16
  split_f32<<<dim3(8192), blk, 0, stream>>>(x, xhi, xlo);

  // Q, K projections: split x @ split wT, split-bf16 output (3-term MFMA)
  gemm_mfma<1, 1, 1, 1><<<dim3(16, 128, 1), blk, 0, stream>>>(
      xhi, xlo, wqThi, wqTlo, bq, qhi, qlo, 8192, 1024, 1024, 0, 0, 0, 1.0f);
  gemm_mfma<1, 1, 1, 1><<<dim3(16, 128, 1), blk, 0, stream>>>(
      xhi, xlo, wkThi, wkTlo, bk, khi, klo, 8192, 1024, 1024, 0, 0, 0, 1.0f);
  // V projection (hi-only), stored transposed per batch: vT[b][d][t]
  gemm_mfma<0, 0, 3, 1><<<dim3(16, 128, 1), blk, 0, stream>>>(
      xhi, nullptr, wvThi, nullptr, bv, vT, nullptr, 8192, 1024, 1024, 0, 0, 0, 1.0f);

  // scores = (q . k) * 32, 3-term split product, fp32 into d_out's p region
  gemm_mfma<1, 1, 2, 0><<<dim3(32, 32, 4), blk, 0, stream>>>(
      qhi, qlo, khi, klo, nullptr, scf, nullptr, 2048, 2048, 1024,
      2048LL * 1024, 2048LL * 1024, 2048LL * 2048, 32.0f);

  // softmax rows: fp32 p in place (d_out) + bf16 p for context
  softmax_rows<<<dim3(8192), blk, 0, stream>>>(scf, pbf);

  // context = p @ v (bf16 out), B = vT[d][t] per batch
  gemm_mfma<0, 0, 0, 0><<<dim3(16, 32, 4), blk, 0, stream>>>(
      pbf, nullptr, vT, nullptr, nullptr, ctx, nullptr, 2048, 1024, 2048,
      2048LL * 2048, 2048LL * 1024, 2048LL * 1024, 1.0f);

  // output = context @ wp + bp, fp32 out
  gemm_mfma<0, 0, 2, 1><<<dim3(16, 128, 1), blk, 0, stream>>>(
      ctx, nullptr, wpThi, nullptr, bp, outp, nullptr, 8192, 1024, 1024, 0, 0, 0, 1.0f);
}

// Round 3
// 534.995 us; speedup vs baseline: 1.2257x; 1.2257x over previous
//
#include <hip/hip_runtime.h>

typedef unsigned short u16;
typedef short bf16x8 __attribute__((ext_vector_type(8)));
typedef float floatx4 __attribute__((ext_vector_type(4)));

// ---------- bf16 helpers (bit-level RNE) --------------------------------------
static __device__ __forceinline__ u16 f2bf(float f) {
  unsigned int u = __float_as_uint(f);
  unsigned int lsb = (u >> 16) & 1u;
  u += 0x7FFFu + lsb;                 // round-to-nearest-even
  return (u16)(u >> 16);
}
static __device__ __forceinline__ float bf2f(u16 u) {
  return __uint_as_float(((unsigned int)u) << 16);
}

// ---------- async global->LDS, 16B per lane (dest = uniform base + lane*16) ----
static __device__ __forceinline__ void gl_lds16(const u16* g, u16* l) {
  __builtin_amdgcn_global_load_lds(
      (const __attribute__((address_space(1))) void*)g,
      (__attribute__((address_space(3))) void*)l, 16, 0, 0);
}

// ---------- fp32 [R][C] -> transposed split-bf16 hi/lo [C][R] ------------------
template<int WANT_LO>
__global__ __launch_bounds__(256)
void split_transpose_f32(const float* __restrict__ in, u16* __restrict__ hi,
                         u16* __restrict__ lo, int R, int C) {
  __shared__ float t[32][33];
  const int r0 = blockIdx.y * 32, c0 = blockIdx.x * 32;
  const int tid = threadIdx.x;
  const int lr = tid >> 3;            // 0..31
  const int lc = (tid & 7) * 4;       // 0,4,..,28
  float4 v = *(const float4*)(in + (size_t)(r0 + lr) * C + c0 + lc);
  t[lr][lc + 0] = v.x; t[lr][lc + 1] = v.y; t[lr][lc + 2] = v.z; t[lr][lc + 3] = v.w;
  __syncthreads();
  u16 ph[4], pl[4];
#pragma unroll
  for (int j = 0; j < 4; j++) {
    float f = t[lc + j][lr];
    ph[j] = f2bf(f);
    if (WANT_LO) pl[j] = f2bf(f - bf2f(ph[j]));
  }
  const size_t o = (size_t)(c0 + lr) * R + r0 + lc;
  *(uint2*)(hi + o) = *(uint2*)ph;
  if (WANT_LO) *(uint2*)(lo + o) = *(uint2*)pl;
}

// ---------- fp32 [n] -> split-bf16 hi/lo (elementwise) -------------------------
__global__ __launch_bounds__(256)
void split_f32(const float* __restrict__ in, u16* __restrict__ hi,
               u16* __restrict__ lo) {
  const size_t i4 = ((size_t)blockIdx.x * 256 + threadIdx.x) * 4;
  float4 v = *(const float4*)(in + i4);
  float f[4] = {v.x, v.y, v.z, v.w};
  u16 ph[4], pl[4];
#pragma unroll
  for (int j = 0; j < 4; j++) {
    ph[j] = f2bf(f[j]);
    pl[j] = f2bf(f[j] - bf2f(ph[j]));
  }
  *(uint2*)(hi + i4) = *(uint2*)ph;
  *(uint2*)(lo + i4) = *(uint2*)pl;
}

// ---------- MFMA GEMM, m97 structure: C[M,N] = A[M,K] * B^T (B stored [N][K]) --
// 128x128 tile / 256 threads (4 waves, each 64x64 = 4x4 frags of 16x16x32), BK=32.
// Staging: global_load_lds 16B/lane into swizzled LDS (logical col-block q of row
// r lives at physical block q ^ ((r>>1)&3)) -> DMA-legal layout AND <=2-way-free
// ds_read_b128 frag reads.
// A_SPLIT/B_SPLIT: hi/lo bf16 planes -> 3-term product (hh + hl + lh).
// OUT_MODE: 0 bf16, 1 split bf16 (hi->C0, lo->C1), 2 fp32,
//           3 bf16 transposed V-store vT[b][n][t], b=m>>11, t=m&2047 (2048x1024)
template<int A_SPLIT, int B_SPLIT, int OUT_MODE, int HAS_BIAS>
__global__ __launch_bounds__(256)
void gemm_mfma(const u16* __restrict__ Ahi, const u16* __restrict__ Alo,
               const u16* __restrict__ Bhi, const u16* __restrict__ Blo,
               const float* __restrict__ bias,
               void* __restrict__ C0, void* __restrict__ C1,
               int M, int N, int K,
               long long aB, long long bB, long long cB, float scale) {
  __shared__ __align__(16) u16 As[(1 + A_SPLIT) * 128 * 32];
  __shared__ __align__(16) u16 Bs[(1 + B_SPLIT) * 128 * 32];

  const int bz = blockIdx.z;
  const u16* A0 = Ahi + (size_t)bz * aB;
  const u16* A1 = A_SPLIT ? (Alo + (size_t)bz * aB) : (const u16*)nullptr;
  const u16* B0 = Bhi + (size_t)bz * bB;
  const u16* B1 = B_SPLIT ? (Blo + (size_t)bz * bB) : (const u16*)nullptr;

  const int m0 = blockIdx.y * 128;
  const int n0 = blockIdx.x * 128;
  const int tid = threadIdx.x;
  const int w = tid >> 6;
  const int L = tid & 63;
  const int rr = L & 15, quad = L >> 4;
  const int wm = (w >> 1) * 64, wn = (w & 1) * 64;

  // staging geometry: wave w stages rows [w*32, w*32+32) of each 128x32 plane,
  // two 1KB issues (16 rows each). Lane L -> row sr + (L>>2), phys col-blk L&3,
  // logical col-blk c3 = (L&3) ^ ((L>>3)&3)  (== (L&3) ^ ((row>>1)&3)).
  const int c3 = (L & 3) ^ ((L >> 3) & 3);
  const int srow = w * 32 + (L >> 2);
  u16* stA = &As[w * 1024];
  u16* stB = &Bs[w * 1024];
  const u16* gA0 = A0 + (size_t)(m0 + srow) * K + c3 * 8;
  const u16* gB0 = B0 + (size_t)(n0 + srow) * K + c3 * 8;
  const u16* gA1 = A_SPLIT ? A1 + (size_t)(m0 + srow) * K + c3 * 8 : (const u16*)nullptr;
  const u16* gB1 = B_SPLIT ? B1 + (size_t)(n0 + srow) * K + c3 * 8 : (const u16*)nullptr;

  // frag-read physical col-block (lane-constant): quad ^ ((rr>>1)&3)
  const int pcb = (quad ^ ((rr >> 1) & 3)) * 8;

  floatx4 acc[4][4] = {};

  for (int k0 = 0; k0 < K; k0 += 32) {
    gl_lds16(gA0 + k0, stA);
    gl_lds16(gA0 + k0 + 16 * (size_t)K, stA + 512);
    gl_lds16(gB0 + k0, stB);
    gl_lds16(gB0 + k0 + 16 * (size_t)K, stB + 512);
    if (A_SPLIT) {
      gl_lds16(gA1 + k0, stA + 4096);
      gl_lds16(gA1 + k0 + 16 * (size_t)K, stA + 4096 + 512);
    }
    if (B_SPLIT) {
      gl_lds16(gB1 + k0, stB + 4096);
      gl_lds16(gB1 + k0 + 16 * (size_t)K, stB + 4096 + 512);
    }
    __syncthreads();                  // drains vmcnt(0) then barrier

    bf16x8 a0[4], a1[4], b0[4], b1[4];
#pragma unroll
    for (int i = 0; i < 4; i++) {
      const int arow = wm + i * 16 + rr;
      const int brow = wn + i * 16 + rr;
      a0[i] = *(const bf16x8*)&As[arow * 32 + pcb];
      if (A_SPLIT) a1[i] = *(const bf16x8*)&As[4096 + arow * 32 + pcb];
      b0[i] = *(const bf16x8*)&Bs[brow * 32 + pcb];
      if (B_SPLIT) b1[i] = *(const bf16x8*)&Bs[4096 + brow * 32 + pcb];
    }
#pragma unroll
    for (int i = 0; i < 4; i++) {
#pragma unroll
      for (int j = 0; j < 4; j++) {
        acc[i][j] = __builtin_amdgcn_mfma_f32_16x16x32_bf16(a0[i], b0[j], acc[i][j], 0, 0, 0);
        if (A_SPLIT && B_SPLIT) {
          acc[i][j] = __builtin_amdgcn_mfma_f32_16x16x32_bf16(a0[i], b1[j], acc[i][j], 0, 0, 0);
          acc[i][j] = __builtin_amdgcn_mfma_f32_16x16x32_bf16(a1[i], b0[j], acc[i][j], 0, 0, 0);
        }
      }
    }
    __syncthreads();                  // all frag reads done before next DMA stage
  }

  // epilogue: D[m = quad*4+ii][n = rr] per 16x16 fragment (m89-verified mapping)
#pragma unroll
  for (int i = 0; i < 4; i++) {
    const int mbase = m0 + wm + i * 16 + quad * 4;
#pragma unroll
    for (int j = 0; j < 4; j++) {
      const int col = n0 + wn + j * 16 + rr;
      float bvs = 0.f;
      if (HAS_BIAS) bvs = bias[col];
      if (OUT_MODE == 3) {
        u16 pk[4];
#pragma unroll
        for (int ii = 0; ii < 4; ii++) pk[ii] = f2bf(acc[i][j][ii] * scale + bvs);
        const size_t idx = (size_t)(mbase >> 11) * (2048 * 1024) + (size_t)col * 2048 + (mbase & 2047);
        *(uint2*)((u16*)C0 + idx) = *(uint2*)pk;
      } else {
        u16* Cb = (u16*)C0 + (size_t)bz * cB;
        float* Cf = (float*)C0 + (size_t)bz * cB;
        u16* Cl = (OUT_MODE == 1) ? ((u16*)C1 + (size_t)bz * cB) : (u16*)nullptr;
#pragma unroll
        for (int ii = 0; ii < 4; ii++) {
          const float v = acc[i][j][ii] * scale + bvs;
          const size_t idx = (size_t)(mbase + ii) * N + col;
          if (OUT_MODE == 0) {
            Cb[idx] = f2bf(v);
          } else if (OUT_MODE == 1) {
            const u16 h = f2bf(v);
            Cb[idx] = h;
            Cl[idx] = f2bf(v - bf2f(h));
          } else if (OUT_MODE == 2) {
            Cf[idx] = v;
          }
        }
      }
    }
  }
}

// ---------- row softmax over 2048 fp32 scores, in place + bf16 copy ------------
__global__ __launch_bounds__(256)
void softmax_rows(float* __restrict__ S, u16* __restrict__ Pb) {
  const int row = blockIdx.x;
  float* s = S + (size_t)row * 2048;
  const int tid = threadIdx.x;
  const int w = tid >> 6;
  __shared__ float redm[4];
  __shared__ float reds[4];

  float v[8];
  float mx = -1e30f;
#pragma unroll
  for (int i = 0; i < 8; i++) {
    v[i] = s[tid + 256 * i];
    mx = fmaxf(mx, v[i]);
  }
#pragma unroll
  for (int o = 32; o > 0; o >>= 1) mx = fmaxf(mx, __shfl_xor(mx, o, 64));
  if ((tid & 63) == 0) redm[w] = mx;
  __syncthreads();
  mx = fmaxf(fmaxf(redm[0], redm[1]), fmaxf(redm[2], redm[3]));

  float sum = 0.f;
#pragma unroll
  for (int i = 0; i < 8; i++) {
    v[i] = __expf(v[i] - mx);
    sum += v[i];
  }
#pragma unroll
  for (int o = 32; o > 0; o >>= 1) sum += __shfl_xor(sum, o, 64);
  if ((tid & 63) == 0) reds[w] = sum;
  __syncthreads();
  sum = reds[0] + reds[1] + reds[2] + reds[3];
  const float rs = 1.0f / sum;
#pragma unroll
  for (int i = 0; i < 8; i++) {
    const float p = v[i] * rs;
    s[tid + 256 * i] = p;                              // fp32 p -> d_out (in place)
    Pb[(size_t)row * 2048 + tid + 256 * i] = f2bf(p);  // bf16 p for context GEMM
  }
}

// ---------- launch ------------------------------------------------------------
extern "C" void kernel_launch(void* const* d_in, const int* in_sizes, int n_in,
                              void* d_out, int out_size, void* d_ws, size_t ws_size,
                              hipStream_t stream) {
  const float* x  = (const float*)d_in[0];
  const float* wq = (const float*)d_in[1];
  const float* bq = (const float*)d_in[2];
  const float* wk = (const float*)d_in[3];
  const float* bk = (const float*)d_in[4];
  const float* wv = (const float*)d_in[5];
  const float* bv = (const float*)d_in[6];
  const float* wp = (const float*)d_in[7];
  const float* bp = (const float*)d_in[8];

  const size_t MB = 1024 * 1024;
  char* ws = (char*)d_ws;
  u16* wqThi = (u16*)(ws + 0 * MB);          // 2 MB each (1024x1024 bf16)
  u16* wqTlo = (u16*)(ws + 2 * MB);
  u16* wkThi = (u16*)(ws + 4 * MB);
  u16* wkTlo = (u16*)(ws + 6 * MB);
  u16* wvThi = (u16*)(ws + 8 * MB);
  u16* wpThi = (u16*)(ws + 10 * MB);
  u16* xhi   = (u16*)(ws + 12 * MB);         // 16 MB each (8192x1024 bf16)
  u16* xlo   = (u16*)(ws + 28 * MB);
  u16* qhi   = (u16*)(ws + 44 * MB);
  u16* qlo   = (u16*)(ws + 60 * MB);
  u16* khi   = (u16*)(ws + 76 * MB);
  u16* klo   = (u16*)(ws + 92 * MB);
  u16* vT    = (u16*)(ws + 108 * MB);        // [b][1024][2048] bf16, 16 MB
  u16* ctx   = qhi;                          // overlay: q dead after scores
  u16* pbf   = khi;                          // overlay: k dead after scores (32 MiB)
  // total ws footprint: 124 MB

  float* outp = (float*)d_out;               // [4,2048,1024] fp32
  float* scf  = (float*)d_out + 8388608;     // scores -> softmax in place -> p fp32

  const dim3 blk(256);

  // weights: fp32 [K][N] -> split-bf16 transposed [N][K]
  split_transpose_f32<1><<<dim3(32, 32), blk, 0, stream>>>(wq, wqThi, wqTlo, 1024, 1024);
  split_transpose_f32<1><<<dim3(32, 32), blk, 0, stream>>>(wk, wkThi, wkTlo, 1024, 1024);
  split_transpose_f32<0><<<dim3(32, 32), blk, 0, stream>>>(wv, wvThi, nullptr, 1024, 1024);
  split_transpose_f32<0><<<dim3(32, 32), blk, 0, stream>>>(wp, wpThi, nullptr, 1024, 1024);
  // x: fp32 -> split-bf16
  split_f32<<<dim3(8192), blk, 0, stream>>>(x, xhi, xlo);

  // Q, K projections: split x @ split wT, split-bf16 output (3-term MFMA)
  gemm_mfma<1, 1, 1, 1><<<dim3(8, 64, 1), blk, 0, stream>>>(
      xhi, xlo, wqThi, wqTlo, bq, qhi, qlo, 8192, 1024, 1024, 0, 0, 0, 1.0f);
  gemm_mfma<1, 1, 1, 1><<<dim3(8, 64, 1), blk, 0, stream>>>(
      xhi, xlo, wkThi, wkTlo, bk, khi, klo, 8192, 1024, 1024, 0, 0, 0, 1.0f);
  // V projection (hi-only), stored transposed per batch: vT[b][d][t]
  gemm_mfma<0, 0, 3, 1><<<dim3(8, 64, 1), blk, 0, stream>>>(
      xhi, nullptr, wvThi, nullptr, bv, vT, nullptr, 8192, 1024, 1024, 0, 0, 0, 1.0f);

  // scores = (q . k) * 32, 3-term split product, fp32 into d_out's p region
  gemm_mfma<1, 1, 2, 0><<<dim3(16, 16, 4), blk, 0, stream>>>(
      qhi, qlo, khi, klo, nullptr, scf, nullptr, 2048, 2048, 1024,
      2048LL * 1024, 2048LL * 1024, 2048LL * 2048, 32.0f);

  // softmax rows: fp32 p in place (d_out) + bf16 p for context
  softmax_rows<<<dim3(8192), blk, 0, stream>>>(scf, pbf);

  // context = p @ v (bf16 out), B = vT[d][t] per batch
  gemm_mfma<0, 0, 0, 0><<<dim3(8, 16, 4), blk, 0, stream>>>(
      pbf, nullptr, vT, nullptr, nullptr, ctx, nullptr, 2048, 1024, 2048,
      2048LL * 2048, 2048LL * 1024, 2048LL * 1024, 1.0f);

  // output = context @ wp + bp, fp32 out
  gemm_mfma<0, 0, 2, 1><<<dim3(8, 64, 1), blk, 0, stream>>>(
      ctx, nullptr, wpThi, nullptr, bp, outp, nullptr, 8192, 1024, 1024, 0, 0, 0, 1.0f);
}

// Round 4
// 514.752 us; speedup vs baseline: 1.2739x; 1.0393x over previous
//
#include <hip/hip_runtime.h>

typedef unsigned short u16;
typedef short bf16x8 __attribute__((ext_vector_type(8)));
typedef float floatx4 __attribute__((ext_vector_type(4)));

// ---------- bf16 helpers (bit-level RNE) --------------------------------------
static __device__ __forceinline__ u16 f2bf(float f) {
  unsigned int u = __float_as_uint(f);
  unsigned int lsb = (u >> 16) & 1u;
  u += 0x7FFFu + lsb;                 // round-to-nearest-even
  return (u16)(u >> 16);
}
static __device__ __forceinline__ float bf2f(u16 u) {
  return __uint_as_float(((unsigned int)u) << 16);
}

// ---------- async global->LDS, 16B per lane (dest = uniform base + lane*16) ----
static __device__ __forceinline__ void gl_lds16(const u16* g, u16* l) {
  __builtin_amdgcn_global_load_lds(
      (const __attribute__((address_space(1))) void*)g,
      (__attribute__((address_space(3))) void*)l, 16, 0, 0);
}

// ---------- weight prep: 4 transposes in one launch ----------------------------
// z=0: wq -> rows    0..1023 of qkThi/qkTlo [2048][1024]
// z=1: wk -> rows 1024..2047 of qkThi/qkTlo
// z=2: wv -> wvThi [1024][1024] (hi only)
// z=3: wp -> wpThi [1024][1024] (hi only)
__global__ __launch_bounds__(256)
void prep_weights(const float* __restrict__ wq, const float* __restrict__ wk,
                  const float* __restrict__ wv, const float* __restrict__ wp,
                  u16* __restrict__ qkThi, u16* __restrict__ qkTlo,
                  u16* __restrict__ wvThi, u16* __restrict__ wpThi) {
  __shared__ float t[32][33];
  const int z = blockIdx.z;
  const float* in = (z == 0) ? wq : (z == 1) ? wk : (z == 2) ? wv : wp;
  u16* hi = (z == 0) ? qkThi : (z == 1) ? (qkThi + 1024 * 1024)
           : (z == 2) ? wvThi : wpThi;
  u16* lo = (z == 0) ? qkTlo : (z == 1) ? (qkTlo + 1024 * 1024) : (u16*)nullptr;
  const int want_lo = (z < 2);

  const int r0 = blockIdx.y * 32, c0 = blockIdx.x * 32;
  const int tid = threadIdx.x;
  const int lr = tid >> 3;            // 0..31
  const int lc = (tid & 7) * 4;       // 0,4,..,28
  float4 v = *(const float4*)(in + (size_t)(r0 + lr) * 1024 + c0 + lc);
  t[lr][lc + 0] = v.x; t[lr][lc + 1] = v.y; t[lr][lc + 2] = v.z; t[lr][lc + 3] = v.w;
  __syncthreads();
  u16 ph[4], pl[4];
#pragma unroll
  for (int j = 0; j < 4; j++) {
    float f = t[lc + j][lr];
    ph[j] = f2bf(f);
    pl[j] = f2bf(f - bf2f(ph[j]));
  }
  const size_t o = (size_t)(c0 + lr) * 1024 + r0 + lc;
  *(uint2*)(hi + o) = *(uint2*)ph;
  if (want_lo) *(uint2*)(lo + o) = *(uint2*)pl;
}

// ---------- bias concat: bqk[2048] = bq | bk ----------------------------------
__global__ __launch_bounds__(256)
void concat_bias(const float* __restrict__ bq, const float* __restrict__ bk,
                 float* __restrict__ out) {
  const int i = blockIdx.x * 256 + threadIdx.x;
  out[i] = (i < 1024) ? bq[i] : bk[i - 1024];
}

// ---------- fp32 [n] -> split-bf16 hi/lo (elementwise) -------------------------
__global__ __launch_bounds__(256)
void split_f32(const float* __restrict__ in, u16* __restrict__ hi,
               u16* __restrict__ lo) {
  const size_t i4 = ((size_t)blockIdx.x * 256 + threadIdx.x) * 4;
  float4 v = *(const float4*)(in + i4);
  float f[4] = {v.x, v.y, v.z, v.w};
  u16 ph[4], pl[4];
#pragma unroll
  for (int j = 0; j < 4; j++) {
    ph[j] = f2bf(f[j]);
    pl[j] = f2bf(f[j] - bf2f(ph[j]));
  }
  *(uint2*)(hi + i4) = *(uint2*)ph;
  *(uint2*)(lo + i4) = *(uint2*)pl;
}

// ---------- MFMA GEMM, m97 structure: C[M,N] = A[M,K] * B^T (B stored [N][K]) --
// 128x128 tile / 256 threads (4 waves, each 64x64 = 4x4 frags of 16x16x32), BK=32.
// T = n-tiles per block (tail elimination: every launch is 512 blocks = 2/CU,
// fully co-resident). Staging: global_load_lds 16B/lane into XOR-swizzled LDS
// (logical col-blk q of row r at phys q ^ ((r>>1)&3)): DMA-legal AND conflict-free.
// A_SPLIT/B_SPLIT: hi/lo bf16 planes -> 3-term product (hh + hl + lh).
// OUT_MODE: 0 bf16, 1 split bf16 (hi->C0, lo->C1), 2 fp32,
//           3 bf16 transposed V-store vT[b][n][t], b=m>>11, t=m&2047 (2048x1024)
template<int A_SPLIT, int B_SPLIT, int OUT_MODE, int HAS_BIAS, int T>
__global__ __launch_bounds__(256)
void gemm_mfma(const u16* __restrict__ Ahi, const u16* __restrict__ Alo,
               const u16* __restrict__ Bhi, const u16* __restrict__ Blo,
               const float* __restrict__ bias,
               void* __restrict__ C0, void* __restrict__ C1,
               int M, int N, int K, int lda, int ldb, int ldc,
               long long aB, long long bB, long long cB, float scale) {
  __shared__ __align__(16) u16 As[(1 + A_SPLIT) * 128 * 32];
  __shared__ __align__(16) u16 Bs[(1 + B_SPLIT) * 128 * 32];

  const int bz = blockIdx.z;
  const u16* A0 = Ahi + (size_t)bz * aB;
  const u16* A1 = A_SPLIT ? (Alo + (size_t)bz * aB) : (const u16*)nullptr;
  const u16* B0 = Bhi + (size_t)bz * bB;
  const u16* B1 = B_SPLIT ? (Blo + (size_t)bz * bB) : (const u16*)nullptr;

  const int m0 = blockIdx.y * 128;
  const int tid = threadIdx.x;
  const int w = tid >> 6;
  const int L = tid & 63;
  const int rr = L & 15, quad = L >> 4;
  const int wm = (w >> 1) * 64, wn = (w & 1) * 64;

  // staging geometry: wave w stages rows [w*32, w*32+32) of each 128x32 plane,
  // two 1KB issues (16 rows each). Lane L -> row srow, phys col-blk L&3,
  // logical col-blk c3 = (L&3) ^ ((L>>3)&3)  (== (L&3) ^ ((row>>1)&3)).
  const int c3 = (L & 3) ^ ((L >> 3) & 3);
  const int srow = w * 32 + (L >> 2);
  u16* stA = &As[w * 1024];
  u16* stB = &Bs[w * 1024];
  const u16* gA0 = A0 + (size_t)(m0 + srow) * lda + c3 * 8;
  const u16* gA1 = A_SPLIT ? A1 + (size_t)(m0 + srow) * lda + c3 * 8 : (const u16*)nullptr;

  // frag-read physical col-block (lane-constant): quad ^ ((rr>>1)&3)
  const int pcb = (quad ^ ((rr >> 1) & 3)) * 8;

  for (int t = 0; t < T; t++) {
    const int n0 = (blockIdx.x * T + t) * 128;
    const u16* gB0 = B0 + (size_t)(n0 + srow) * ldb + c3 * 8;
    const u16* gB1 = B_SPLIT ? B1 + (size_t)(n0 + srow) * ldb + c3 * 8 : (const u16*)nullptr;

    floatx4 acc[4][4] = {};

    for (int k0 = 0; k0 < K; k0 += 32) {
      gl_lds16(gA0 + k0, stA);
      gl_lds16(gA0 + k0 + 16 * (size_t)lda, stA + 512);
      gl_lds16(gB0 + k0, stB);
      gl_lds16(gB0 + k0 + 16 * (size_t)ldb, stB + 512);
      if (A_SPLIT) {
        gl_lds16(gA1 + k0, stA + 4096);
        gl_lds16(gA1 + k0 + 16 * (size_t)lda, stA + 4096 + 512);
      }
      if (B_SPLIT) {
        gl_lds16(gB1 + k0, stB + 4096);
        gl_lds16(gB1 + k0 + 16 * (size_t)ldb, stB + 4096 + 512);
      }
      __syncthreads();                // drains vmcnt(0) then barrier

      bf16x8 a0[4], a1[4], b0[4], b1[4];
#pragma unroll
      for (int i = 0; i < 4; i++) {
        const int arow = wm + i * 16 + rr;
        const int brow = wn + i * 16 + rr;
        a0[i] = *(const bf16x8*)&As[arow * 32 + pcb];
        if (A_SPLIT) a1[i] = *(const bf16x8*)&As[4096 + arow * 32 + pcb];
        b0[i] = *(const bf16x8*)&Bs[brow * 32 + pcb];
        if (B_SPLIT) b1[i] = *(const bf16x8*)&Bs[4096 + brow * 32 + pcb];
      }
#pragma unroll
      for (int i = 0; i < 4; i++) {
#pragma unroll
        for (int j = 0; j < 4; j++) {
          acc[i][j] = __builtin_amdgcn_mfma_f32_16x16x32_bf16(a0[i], b0[j], acc[i][j], 0, 0, 0);
          if (A_SPLIT && B_SPLIT) {
            acc[i][j] = __builtin_amdgcn_mfma_f32_16x16x32_bf16(a0[i], b1[j], acc[i][j], 0, 0, 0);
            acc[i][j] = __builtin_amdgcn_mfma_f32_16x16x32_bf16(a1[i], b0[j], acc[i][j], 0, 0, 0);
          }
        }
      }
      __syncthreads();                // all frag reads done before next DMA stage
    }

    // epilogue: D[m = quad*4+ii][n = rr] per 16x16 fragment (m89-verified)
#pragma unroll
    for (int i = 0; i < 4; i++) {
      const int mbase = m0 + wm + i * 16 + quad * 4;
#pragma unroll
      for (int j = 0; j < 4; j++) {
        const int col = n0 + wn + j * 16 + rr;
        float bvs = 0.f;
        if (HAS_BIAS) bvs = bias[col];
        if (OUT_MODE == 3) {
          u16 pk[4];
#pragma unroll
          for (int ii = 0; ii < 4; ii++) pk[ii] = f2bf(acc[i][j][ii] * scale + bvs);
          const size_t idx = (size_t)(mbase >> 11) * (2048 * 1024) + (size_t)col * 2048 + (mbase & 2047);
          *(uint2*)((u16*)C0 + idx) = *(uint2*)pk;
        } else {
          u16* Cb = (u16*)C0 + (size_t)bz * cB;
          float* Cf = (float*)C0 + (size_t)bz * cB;
          u16* Cl = (OUT_MODE == 1) ? ((u16*)C1 + (size_t)bz * cB) : (u16*)nullptr;
#pragma unroll
          for (int ii = 0; ii < 4; ii++) {
            const float v = acc[i][j][ii] * scale + bvs;
            const size_t idx = (size_t)(mbase + ii) * ldc + col;
            if (OUT_MODE == 0) {
              Cb[idx] = f2bf(v);
            } else if (OUT_MODE == 1) {
              const u16 h = f2bf(v);
              Cb[idx] = h;
              Cl[idx] = f2bf(v - bf2f(h));
            } else if (OUT_MODE == 2) {
              Cf[idx] = v;
            }
          }
        }
      }
    }
  }
}

// ---------- row softmax over 2048 fp32 scores, in place + bf16 copy ------------
__global__ __launch_bounds__(256)
void softmax_rows(float* __restrict__ S, u16* __restrict__ Pb) {
  const int row = blockIdx.x;
  float* s = S + (size_t)row * 2048;
  const int tid = threadIdx.x;
  const int w = tid >> 6;
  __shared__ float redm[4];
  __shared__ float reds[4];

  float v[8];
  float mx = -1e30f;
#pragma unroll
  for (int i = 0; i < 8; i++) {
    v[i] = s[tid + 256 * i];
    mx = fmaxf(mx, v[i]);
  }
#pragma unroll
  for (int o = 32; o > 0; o >>= 1) mx = fmaxf(mx, __shfl_xor(mx, o, 64));
  if ((tid & 63) == 0) redm[w] = mx;
  __syncthreads();
  mx = fmaxf(fmaxf(redm[0], redm[1]), fmaxf(redm[2], redm[3]));

  float sum = 0.f;
#pragma unroll
  for (int i = 0; i < 8; i++) {
    v[i] = __expf(v[i] - mx);
    sum += v[i];
  }
#pragma unroll
  for (int o = 32; o > 0; o >>= 1) sum += __shfl_xor(sum, o, 64);
  if ((tid & 63) == 0) reds[w] = sum;
  __syncthreads();
  sum = reds[0] + reds[1] + reds[2] + reds[3];
  const float rs = 1.0f / sum;
#pragma unroll
  for (int i = 0; i < 8; i++) {
    const float p = v[i] * rs;
    s[tid + 256 * i] = p;                              // fp32 p -> d_out (in place)
    Pb[(size_t)row * 2048 + tid + 256 * i] = f2bf(p);  // bf16 p for context GEMM
  }
}

// ---------- launch ------------------------------------------------------------
extern "C" void kernel_launch(void* const* d_in, const int* in_sizes, int n_in,
                              void* d_out, int out_size, void* d_ws, size_t ws_size,
                              hipStream_t stream) {
  const float* x  = (const float*)d_in[0];
  const float* wq = (const float*)d_in[1];
  const float* bq = (const float*)d_in[2];
  const float* wk = (const float*)d_in[3];
  const float* bk = (const float*)d_in[4];
  const float* wv = (const float*)d_in[5];
  const float* bv = (const float*)d_in[6];
  const float* wp = (const float*)d_in[7];
  const float* bp = (const float*)d_in[8];

  const size_t MB = 1024 * 1024;
  char* ws = (char*)d_ws;
  u16* qkThi = (u16*)(ws + 0 * MB);          // [2048][1024] bf16, 4 MB
  u16* qkTlo = (u16*)(ws + 4 * MB);
  u16* wvThi = (u16*)(ws + 8 * MB);          // 2 MB each
  u16* wpThi = (u16*)(ws + 10 * MB);
  float* bqk = (float*)(ws + 12 * MB);       // 8 KB
  u16* xhi   = (u16*)(ws + 13 * MB);         // 16 MB each (8192x1024 bf16)
  u16* xlo   = (u16*)(ws + 29 * MB);
  u16* qkhi  = (u16*)(ws + 45 * MB);         // [8192][2048] bf16, 32 MB
  u16* qklo  = (u16*)(ws + 77 * MB);         // 32 MB
  u16* vT    = (u16*)(ws + 109 * MB);        // [b][1024][2048] bf16, 16 MB
  u16* pbf   = qklo;                         // overlay: qk lo dead after scores
  u16* ctx   = qkhi;                         // overlay: qk hi dead after scores
  // total ws footprint: 125 MB

  float* outp = (float*)d_out;               // [4,2048,1024] fp32
  float* scf  = (float*)d_out + 8388608;     // scores -> softmax in place -> p fp32

  const dim3 blk(256);

  prep_weights<<<dim3(32, 32, 4), blk, 0, stream>>>(wq, wk, wv, wp,
                                                    qkThi, qkTlo, wvThi, wpThi);
  concat_bias<<<dim3(8), blk, 0, stream>>>(bq, bk, bqk);
  split_f32<<<dim3(8192), blk, 0, stream>>>(x, xhi, xlo);

  // fused Q|K projection: [8192,2048] = x @ [wq|wk], 3-term split, split out
  gemm_mfma<1, 1, 1, 1, 2><<<dim3(8, 64, 1), blk, 0, stream>>>(
      xhi, xlo, qkThi, qkTlo, bqk, qkhi, qklo,
      8192, 2048, 1024, 1024, 1024, 2048, 0, 0, 0, 1.0f);

  // V projection (hi-only), stored transposed per batch: vT[b][d][t]
  gemm_mfma<0, 0, 3, 1, 1><<<dim3(8, 64, 1), blk, 0, stream>>>(
      xhi, nullptr, wvThi, nullptr, bv, vT, nullptr,
      8192, 1024, 1024, 1024, 1024, 0, 0, 0, 0, 1.0f);

  // scores = (q . k) * 32: A = q cols of qk, B = k cols of qk, fp32 out
  gemm_mfma<1, 1, 2, 0, 2><<<dim3(8, 16, 4), blk, 0, stream>>>(
      qkhi, qklo, qkhi + 1024, qklo + 1024, nullptr, scf, nullptr,
      2048, 2048, 1024, 2048, 2048, 2048,
      2048LL * 2048, 2048LL * 2048, 2048LL * 2048, 32.0f);

  // softmax rows: fp32 p in place (d_out) + bf16 p for context
  softmax_rows<<<dim3(8192), blk, 0, stream>>>(scf, pbf);

  // context = p @ v (bf16 out), B = vT[d][t] per batch
  gemm_mfma<0, 0, 0, 0, 1><<<dim3(8, 16, 4), blk, 0, stream>>>(
      pbf, nullptr, vT, nullptr, nullptr, ctx, nullptr,
      2048, 1024, 2048, 2048, 2048, 1024,
      2048LL * 2048, 1024LL * 2048, 2048LL * 1024, 1.0f);

  // output = context @ wp + bp, fp32 out
  gemm_mfma<0, 0, 2, 1, 1><<<dim3(8, 64, 1), blk, 0, stream>>>(
      ctx, nullptr, wpThi, nullptr, bp, outp, nullptr,
      8192, 1024, 1024, 1024, 1024, 1024, 0, 0, 0, 1.0f);
}

// Round 5
// 513.092 us; speedup vs baseline: 1.2780x; 1.0032x over previous
//
#include <hip/hip_runtime.h>

typedef unsigned short u16;
typedef short bf16x8 __attribute__((ext_vector_type(8)));
typedef float floatx4 __attribute__((ext_vector_type(4)));

// ---------- bf16 helpers (bit-level RNE) --------------------------------------
static __device__ __forceinline__ u16 f2bf(float f) {
  unsigned int u = __float_as_uint(f);
  unsigned int lsb = (u >> 16) & 1u;
  u += 0x7FFFu + lsb;                 // round-to-nearest-even
  return (u16)(u >> 16);
}
static __device__ __forceinline__ float bf2f(u16 u) {
  return __uint_as_float(((unsigned int)u) << 16);
}

// ---------- async global->LDS, 16B per lane (dest = uniform base + lane*16) ----
static __device__ __forceinline__ void gl_lds16(const u16* g, u16* l) {
  __builtin_amdgcn_global_load_lds(
      (const __attribute__((address_space(1))) void*)g,
      (__attribute__((address_space(3))) void*)l, 16, 0, 0);
}

// ---------- weight prep: 4 transposes + bias concat in one launch --------------
// z=0: wq -> rows    0..1023 of qkvThi/qkvTlo
// z=1: wk -> rows 1024..2047 of qkvThi/qkvTlo
// z=2: wv -> rows 2048..3071 of qkvThi (hi only)
// z=3: wp -> wpThi (hi only)
// z=4: (x<12, y==0) bias concat bqkv[3072] = bq|bk|bv
__global__ __launch_bounds__(256)
void prep_weights(const float* __restrict__ wq, const float* __restrict__ wk,
                  const float* __restrict__ wv, const float* __restrict__ wp,
                  const float* __restrict__ bq, const float* __restrict__ bk,
                  const float* __restrict__ bv,
                  u16* __restrict__ qkvThi, u16* __restrict__ qkvTlo,
                  u16* __restrict__ wpThi, float* __restrict__ bqkv) {
  __shared__ float t[32][33];
  const int z = blockIdx.z;
  const int tid = threadIdx.x;
  if (z == 4) {
    if (blockIdx.y == 0 && blockIdx.x < 12) {
      const int i = blockIdx.x * 256 + tid;
      bqkv[i] = (i < 1024) ? bq[i] : (i < 2048) ? bk[i - 1024] : bv[i - 2048];
    }
    return;
  }
  const float* in = (z == 0) ? wq : (z == 1) ? wk : (z == 2) ? wv : wp;
  u16* hi = (z == 3) ? wpThi : (qkvThi + (size_t)z * 1024 * 1024);
  u16* lo = (z == 0) ? qkvTlo : (z == 1) ? (qkvTlo + 1024 * 1024) : (u16*)nullptr;
  const int want_lo = (z < 2);

  const int r0 = blockIdx.y * 32, c0 = blockIdx.x * 32;
  const int lr = tid >> 3;            // 0..31
  const int lc = (tid & 7) * 4;       // 0,4,..,28
  float4 v = *(const float4*)(in + (size_t)(r0 + lr) * 1024 + c0 + lc);
  t[lr][lc + 0] = v.x; t[lr][lc + 1] = v.y; t[lr][lc + 2] = v.z; t[lr][lc + 3] = v.w;
  __syncthreads();
  u16 ph[4], pl[4];
#pragma unroll
  for (int j = 0; j < 4; j++) {
    float f = t[lc + j][lr];
    ph[j] = f2bf(f);
    pl[j] = f2bf(f - bf2f(ph[j]));
  }
  const size_t o = (size_t)(c0 + lr) * 1024 + r0 + lc;
  *(uint2*)(hi + o) = *(uint2*)ph;
  if (want_lo) *(uint2*)(lo + o) = *(uint2*)pl;
}

// ---------- fp32 [n] -> split-bf16 hi/lo (elementwise) -------------------------
__global__ __launch_bounds__(256)
void split_f32(const float* __restrict__ in, u16* __restrict__ hi,
               u16* __restrict__ lo) {
  const size_t i4 = ((size_t)blockIdx.x * 256 + threadIdx.x) * 4;
  float4 v = *(const float4*)(in + i4);
  float f[4] = {v.x, v.y, v.z, v.w};
  u16 ph[4], pl[4];
#pragma unroll
  for (int j = 0; j < 4; j++) {
    ph[j] = f2bf(f[j]);
    pl[j] = f2bf(f[j] - bf2f(ph[j]));
  }
  *(uint2*)(hi + i4) = *(uint2*)ph;
  *(uint2*)(lo + i4) = *(uint2*)pl;
}

// ---------- MFMA GEMM, m97 structure: C[M,N] = A[M,K] * B^T (B stored [N][K]) --
// 128x128 tile / 256 threads (4 waves, each 64x64 = 4x4 frags of 16x16x32).
// KB = K-tile (32 or 64). Staging: global_load_lds 16B/lane into XOR-swizzled
// LDS; swizzle field matches bank geometry per KB (KB32: c^((r>>1)&3) on 64B
// rows; KB64: c^(r&7) on 128B rows) -> DMA-legal AND bank-balanced b128 reads.
// ASP/BSP: hi/lo bf16 planes -> 3-term product (hh+hl+lh), runtime-gated per
// n-tile by (n0 < nsplit) so fused QKV can do 1-term V tiles.
// OM: 0 bf16 out, 2 fp32 out, 4 fused-QKV out (col<1024 -> split q planes,
//     col<2048 -> split k planes, else transposed vT[b][d][t] store).
template<int KB, int ASP, int BSP, int OM, int HB>
__global__ __launch_bounds__(256)
void gemm_mfma(const u16* __restrict__ Ahi, const u16* __restrict__ Alo,
               const u16* __restrict__ Bhi, const u16* __restrict__ Blo,
               const float* __restrict__ bias,
               void* __restrict__ C0, void* __restrict__ C1,
               void* __restrict__ C2, void* __restrict__ C3,
               void* __restrict__ C4,
               int N, int K, int lda, int ldb, int ldc,
               long long aB, long long bB, long long cB, float scale,
               int nsplit) {
  constexpr int CM = KB / 8 - 1;      // col-block mask (3 or 7)
  constexpr int RPI = 512 / KB;       // rows per 1KB DMA issue (16 or 8)
  constexpr int NI = KB / 16;         // issues per wave per plane (2 or 4)
  constexpr int PL = 128 * KB;        // plane elems
  __shared__ __align__(16) u16 As[(1 + ASP) * PL];
  __shared__ __align__(16) u16 Bs[(1 + BSP) * PL];

  const int bz = blockIdx.z;
  const u16* A0 = Ahi + (size_t)bz * aB;
  const u16* A1 = ASP ? (Alo + (size_t)bz * aB) : (const u16*)nullptr;
  const u16* B0 = Bhi + (size_t)bz * bB;
  const u16* B1 = BSP ? (Blo + (size_t)bz * bB) : (const u16*)nullptr;

  const int m0 = blockIdx.y * 128;
  const int n0 = blockIdx.x * 128;
  const bool bsplit = (ASP && BSP) ? (n0 < nsplit) : false;
  const int tid = threadIdx.x;
  const int w = tid >> 6;
  const int L = tid & 63;
  const int rr = L & 15, quad = L >> 4;
  const int wm = (w >> 1) * 64, wn = (w & 1) * 64;

  // staging geometry: wave w stages rows [w*32, w*32+32) of each 128xKB plane.
  const int lrow = (KB == 32) ? (L >> 2) : (L >> 3);
  const int c3 = (L & CM) ^ ((L >> 3) & CM);    // global (logical) col-block
  const int srow = w * 32 + lrow;
  u16* stA = &As[w * 32 * KB];
  u16* stB = &Bs[w * 32 * KB];
  const u16* gA0 = A0 + (size_t)(m0 + srow) * lda + c3 * 8;
  const u16* gA1 = ASP ? A1 + (size_t)(m0 + srow) * lda + c3 * 8 : (const u16*)nullptr;
  const u16* gB0 = B0 + (size_t)(n0 + srow) * ldb + c3 * 8;
  const u16* gB1 = BSP ? B1 + (size_t)(n0 + srow) * ldb + c3 * 8 : (const u16*)nullptr;

  floatx4 acc[4][4] = {};

  for (int k0 = 0; k0 < K; k0 += KB) {
#pragma unroll
    for (int q = 0; q < NI; q++) {
      gl_lds16(gA0 + k0 + (size_t)q * RPI * lda, stA + q * 512);
      gl_lds16(gB0 + k0 + (size_t)q * RPI * ldb, stB + q * 512);
    }
    if (ASP && bsplit) {
#pragma unroll
      for (int q = 0; q < NI; q++)
        gl_lds16(gA1 + k0 + (size_t)q * RPI * lda, stA + PL + q * 512);
    }
    if (BSP && bsplit) {
#pragma unroll
      for (int q = 0; q < NI; q++)
        gl_lds16(gB1 + k0 + (size_t)q * RPI * ldb, stB + PL + q * 512);
    }
    __syncthreads();                  // drains vmcnt(0) then barrier

#pragma unroll
    for (int s = 0; s < KB / 32; s++) {
      // frag phys col-block for logical k-chunk s (lane-constant)
      const int pcb = (KB == 32) ? (quad ^ ((rr >> 1) & 3)) * 8
                                 : ((s * 4 + quad) ^ (rr & 7)) * 8;
      bf16x8 a0[4], a1[4], b0[4], b1[4];
#pragma unroll
      for (int i = 0; i < 4; i++) {
        const int arow = wm + i * 16 + rr;
        const int brow = wn + i * 16 + rr;
        a0[i] = *(const bf16x8*)&As[arow * KB + pcb];
        b0[i] = *(const bf16x8*)&Bs[brow * KB + pcb];
        if (ASP && BSP) {
          if (bsplit) {
            a1[i] = *(const bf16x8*)&As[PL + arow * KB + pcb];
            b1[i] = *(const bf16x8*)&Bs[PL + brow * KB + pcb];
          }
        }
      }
#pragma unroll
      for (int i = 0; i < 4; i++) {
#pragma unroll
        for (int j = 0; j < 4; j++) {
          acc[i][j] = __builtin_amdgcn_mfma_f32_16x16x32_bf16(a0[i], b0[j], acc[i][j], 0, 0, 0);
          if (ASP && BSP) {
            if (bsplit) {
              acc[i][j] = __builtin_amdgcn_mfma_f32_16x16x32_bf16(a0[i], b1[j], acc[i][j], 0, 0, 0);
              acc[i][j] = __builtin_amdgcn_mfma_f32_16x16x32_bf16(a1[i], b0[j], acc[i][j], 0, 0, 0);
            }
          }
        }
      }
    }
    __syncthreads();                  // all frag reads done before next DMA stage
  }

  // epilogue: D[m = quad*4+ii][n = rr] per 16x16 fragment (m89-verified)
#pragma unroll
  for (int i = 0; i < 4; i++) {
    const int mbase = m0 + wm + i * 16 + quad * 4;
#pragma unroll
    for (int j = 0; j < 4; j++) {
      const int col = n0 + wn + j * 16 + rr;
      float bvs = 0.f;
      if (HB) bvs = bias[col];
      if (OM == 4) {
        if (col < 2048) {
          u16* hi; u16* lo;
          if (col < 1024) { hi = (u16*)C0; lo = (u16*)C1; }
          else            { hi = (u16*)C2; lo = (u16*)C3; }
          const int cc = col & 1023;
#pragma unroll
          for (int ii = 0; ii < 4; ii++) {
            const float v = acc[i][j][ii] + bvs;
            const size_t idx = (size_t)(mbase + ii) * 1024 + cc;
            const u16 h = f2bf(v);
            hi[idx] = h;
            lo[idx] = f2bf(v - bf2f(h));
          }
        } else {
          const int d = col - 2048;
          u16 pk[4];
#pragma unroll
          for (int ii = 0; ii < 4; ii++) pk[ii] = f2bf(acc[i][j][ii] + bvs);
          const size_t idx = (size_t)(mbase >> 11) * (2048 * 1024) +
                             (size_t)d * 2048 + (mbase & 2047);
          *(uint2*)((u16*)C4 + idx) = *(uint2*)pk;
        }
      } else {
        u16* Cb = (u16*)C0 + (size_t)bz * cB;
        float* Cf = (float*)C0 + (size_t)bz * cB;
#pragma unroll
        for (int ii = 0; ii < 4; ii++) {
          const float v = acc[i][j][ii] * scale + bvs;
          const size_t idx = (size_t)(mbase + ii) * ldc + col;
          if (OM == 0) Cb[idx] = f2bf(v);
          else         Cf[idx] = v;
        }
      }
    }
  }
}

// ---------- row softmax over 2048 fp32 scores, in place + bf16 copy ------------
__global__ __launch_bounds__(256)
void softmax_rows(float* __restrict__ S, u16* __restrict__ Pb) {
  const int row = blockIdx.x;
  float* s = S + (size_t)row * 2048;
  const int tid = threadIdx.x;
  const int w = tid >> 6;
  __shared__ float redm[4];
  __shared__ float reds[4];

  float v[8];
  float mx = -1e30f;
#pragma unroll
  for (int i = 0; i < 8; i++) {
    v[i] = s[tid + 256 * i];
    mx = fmaxf(mx, v[i]);
  }
#pragma unroll
  for (int o = 32; o > 0; o >>= 1) mx = fmaxf(mx, __shfl_xor(mx, o, 64));
  if ((tid & 63) == 0) redm[w] = mx;
  __syncthreads();
  mx = fmaxf(fmaxf(redm[0], redm[1]), fmaxf(redm[2], redm[3]));

  float sum = 0.f;
#pragma unroll
  for (int i = 0; i < 8; i++) {
    v[i] = __expf(v[i] - mx);
    sum += v[i];
  }
#pragma unroll
  for (int o = 32; o > 0; o >>= 1) sum += __shfl_xor(sum, o, 64);
  if ((tid & 63) == 0) reds[w] = sum;
  __syncthreads();
  sum = reds[0] + reds[1] + reds[2] + reds[3];
  const float rs = 1.0f / sum;
#pragma unroll
  for (int i = 0; i < 8; i++) {
    const float p = v[i] * rs;
    s[tid + 256 * i] = p;                              // fp32 p -> d_out (in place)
    Pb[(size_t)row * 2048 + tid + 256 * i] = f2bf(p);  // bf16 p for context GEMM
  }
}

// ---------- launch ------------------------------------------------------------
extern "C" void kernel_launch(void* const* d_in, const int* in_sizes, int n_in,
                              void* d_out, int out_size, void* d_ws, size_t ws_size,
                              hipStream_t stream) {
  const float* x  = (const float*)d_in[0];
  const float* wq = (const float*)d_in[1];
  const float* bq = (const float*)d_in[2];
  const float* wk = (const float*)d_in[3];
  const float* bk = (const float*)d_in[4];
  const float* wv = (const float*)d_in[5];
  const float* bv = (const float*)d_in[6];
  const float* wp = (const float*)d_in[7];
  const float* bp = (const float*)d_in[8];

  const size_t MB = 1024 * 1024;
  char* ws = (char*)d_ws;
  u16* qkvThi = (u16*)(ws + 0 * MB);         // [3072][1024] bf16, 6 MB
  u16* qkvTlo = (u16*)(ws + 6 * MB);         // [2048][1024] bf16, 4 MB
  u16* wpThi  = (u16*)(ws + 10 * MB);        // 2 MB
  float* bqkv = (float*)(ws + 12 * MB);      // 12 KB
  u16* xhi    = (u16*)(ws + 13 * MB);        // 16 MB each (8192x1024 bf16)
  u16* xlo    = (u16*)(ws + 29 * MB);
  u16* qhi    = (u16*)(ws + 45 * MB);
  u16* qlo    = (u16*)(ws + 61 * MB);
  u16* khi    = (u16*)(ws + 77 * MB);
  u16* klo    = (u16*)(ws + 93 * MB);
  u16* vT     = (u16*)(ws + 109 * MB);       // [b][1024][2048] bf16, 16 MB
  u16* pbf    = khi;                         // overlay: k dead after scores, 32 MB
  u16* ctx    = qhi;                         // overlay: q dead after scores, 16 MB
  // total ws footprint: 125 MB

  float* outp = (float*)d_out;               // [4,2048,1024] fp32
  float* scf  = (float*)d_out + 8388608;     // scores -> softmax in place -> p fp32

  const dim3 blk(256);

  prep_weights<<<dim3(32, 32, 5), blk, 0, stream>>>(
      wq, wk, wv, wp, bq, bk, bv, qkvThi, qkvTlo, wpThi, bqkv);
  split_f32<<<dim3(8192), blk, 0, stream>>>(x, xhi, xlo);

  // fused Q|K|V projection: N=3072; qk tiles 3-term split -> planar q/k planes;
  // v tiles (n0>=2048) 1-term -> transposed vT store. 1536 blocks = 2x768.
  gemm_mfma<32, 1, 1, 4, 1><<<dim3(24, 64, 1), blk, 0, stream>>>(
      xhi, xlo, qkvThi, qkvTlo, bqkv, qhi, qlo, khi, klo, vT,
      3072, 1024, 1024, 1024, 0, 0, 0, 0, 1.0f, 2048);

  // scores = (q . k) * 32, 3-term split, fp32 into d_out's p region (round-3 cfg)
  gemm_mfma<32, 1, 1, 2, 0><<<dim3(16, 16, 4), blk, 0, stream>>>(
      qhi, qlo, khi, klo, nullptr, scf, nullptr, nullptr, nullptr, nullptr,
      2048, 1024, 1024, 1024, 2048,
      2048LL * 1024, 2048LL * 1024, 2048LL * 2048, 32.0f, 2048);

  // softmax rows: fp32 p in place (d_out) + bf16 p for context
  softmax_rows<<<dim3(8192), blk, 0, stream>>>(scf, pbf);

  // context = p @ v (bf16 out), B = vT[d][t] per batch; KB=64
  gemm_mfma<64, 0, 0, 0, 0><<<dim3(8, 16, 4), blk, 0, stream>>>(
      pbf, nullptr, vT, nullptr, nullptr, ctx, nullptr, nullptr, nullptr, nullptr,
      1024, 2048, 2048, 2048, 1024,
      2048LL * 2048, 1024LL * 2048, 2048LL * 1024, 1.0f, 0);

  // output = context @ wp + bp, fp32 out; KB=64
  gemm_mfma<64, 0, 0, 2, 1><<<dim3(8, 64, 1), blk, 0, stream>>>(
      ctx, nullptr, wpThi, nullptr, bp, outp, nullptr, nullptr, nullptr, nullptr,
      1024, 1024, 1024, 1024, 1024, 0, 0, 0, 1.0f, 0);
}